// Round 9
// baseline (240.926 us; speedup 1.0000x reference)
//
#include <hip/hip_runtime.h>
#include <math.h>

// ---------------- problem constants ----------------
#define NB        512
#define ND        32
#define NCOND     30
#define NS        21                  // NB_STEPS+1 quadrature nodes
#define NBD       (NB*ND)             // 16384
#define NROWS     (NBD*NS)            // 344064 MLP evaluations
#define MBLK      64                  // rows per block
#define NBLOCKS   (NROWS/MBLK)        // 5376

// packed-weight element counts (ushort)
#define W0P_ELEMS (1*16*64*8)         // 8192
#define W1P_ELEMS (8*16*64*8)         // 65536
#define W3P_ELEMS (8*64*8)            // 4096  (zero-padded W3 as A-fragments)
#define WP_TOTAL  (W0P_ELEMS + 2*W1P_ELEMS + W3P_ELEMS)  // 143360

typedef __bf16 bf8 __attribute__((ext_vector_type(8)));
typedef float  fx4 __attribute__((ext_vector_type(4)));
typedef unsigned short us8 __attribute__((ext_vector_type(8)));

__device__ __forceinline__ unsigned short f2bf(float f) {
  unsigned int u = __float_as_uint(f);
  u += 0x7FFFu + ((u >> 16) & 1u);        // round-to-nearest-even
  return (unsigned short)(u >> 16);
}

// ---------------- kernel 1: pack weights to bf16 MFMA fragment order ----------
__global__ void prep_pack(const float* __restrict__ W0,
                          const float* __restrict__ W1,
                          const float* __restrict__ W2,
                          const float* __restrict__ W3,
                          unsigned short* __restrict__ wp) {
  int t = blockIdx.x * blockDim.x + threadIdx.x;   // one thread = one 8-elem frag
  if (t >= WP_TOTAL / 8) return;
  int base = t * 8;
  us8 out;
  if (base >= W0P_ELEMS + 2 * W1P_ELEMS) {         // W3 region
    int rem  = base - (W0P_ELEMS + 2 * W1P_ELEMS);
    int lane = (rem >> 3) & 63;
    int ktl  = rem >> 9;
    int k0   = ktl * 32 + (lane >> 4) * 8;
#pragma unroll
    for (int i = 0; i < 8; ++i)
      out[i] = ((lane & 15) == 0) ? f2bf(W3[k0 + i]) : (unsigned short)0;
  } else {
    const float* W; int rem, K;
    if (base < W0P_ELEMS)                  { W = W0; rem = base;                 K = 31;  }
    else if (base < W0P_ELEMS + W1P_ELEMS) { W = W1; rem = base - W0P_ELEMS;     K = 256; }
    else                                   { W = W2; rem = base - W0P_ELEMS - W1P_ELEMS; K = 256; }
    int lane = (rem >> 3) & 63;
    int ct   = (rem >> 9) & 15;
    int ktl  =  rem >> 13;
    int j  = ct * 16 + (lane & 15);
    int k0 = ktl * 32 + (lane >> 4) * 8;
#pragma unroll
    for (int i = 0; i < 8; ++i) {
      int k = k0 + i;
      out[i] = (k < K) ? f2bf(W[k * 256 + j]) : (unsigned short)0;
    }
  }
  *reinterpret_cast<us8*>(wp + base) = out;
}

// ---------------- fused MLP kernel ----------------
// 4 waves/block (256 thr), block = 64 rows. Wave wv owns ALL 64 rows
// (4 row-tiles) x 64 neurons (cgrp = wv). Same per-wave tile as rounds 6-8
// but half the block: 4 independent 4-wave barrier groups per CU instead of
// two 8-wave lockstep groups (R8 falsified the LDS theory; VGPR cap 512/N and
// blocks/CU launch_bounds semantics confirmed). (256,4) -> cap 128 VGPR,
// 4 blocks/CU co-resident, LDS 32 KB/block. In-place act buffer + depth-2
// weight pipeline + setprio unchanged.

#define ACC_ZERO                                                                 \
  _Pragma("unroll")                                                              \
  for (int rt = 0; rt < 4; ++rt)                                                 \
    _Pragma("unroll")                                                            \
    for (int ct = 0; ct < 4; ++ct) acc[rt][ct] = fx4{0.f, 0.f, 0.f, 0.f};

#define LOADW4(S0,S1,S2,S3, WB, KT)                                              \
  S0 = *reinterpret_cast<const bf8*>((WB) + (((KT) * 16 + cgrp * 4 + 0) * 64 + lane) * 8); \
  S1 = *reinterpret_cast<const bf8*>((WB) + (((KT) * 16 + cgrp * 4 + 1) * 64 + lane) * 8); \
  S2 = *reinterpret_cast<const bf8*>((WB) + (((KT) * 16 + cgrp * 4 + 2) * 64 + lane) * 8); \
  S3 = *reinterpret_cast<const bf8*>((WB) + (((KT) * 16 + cgrp * 4 + 3) * 64 + lane) * 8);

#define KSTEP(W0_,W1_,W2_,W3_, KT)                                               \
  {                                                                              \
    int m0 =  0 + colb;                                                          \
    int m1 = 16 + colb;                                                          \
    int m2 = 32 + colb;                                                          \
    int m3 = 48 + colb;                                                          \
    bf8 a0 = *reinterpret_cast<const bf8*>(ldsAct + (((unsigned)(m0 * 512 + (KT) * 64 + khalf * 16)) ^ ((unsigned)((m0 & 15) << 4)))); \
    bf8 a1 = *reinterpret_cast<const bf8*>(ldsAct + (((unsigned)(m1 * 512 + (KT) * 64 + khalf * 16)) ^ ((unsigned)((m1 & 15) << 4)))); \
    bf8 a2 = *reinterpret_cast<const bf8*>(ldsAct + (((unsigned)(m2 * 512 + (KT) * 64 + khalf * 16)) ^ ((unsigned)((m2 & 15) << 4)))); \
    bf8 a3 = *reinterpret_cast<const bf8*>(ldsAct + (((unsigned)(m3 * 512 + (KT) * 64 + khalf * 16)) ^ ((unsigned)((m3 & 15) << 4)))); \
    __builtin_amdgcn_s_setprio(1);                                               \
    acc[0][0] = __builtin_amdgcn_mfma_f32_16x16x32_bf16(W0_, a0, acc[0][0], 0, 0, 0); \
    acc[0][1] = __builtin_amdgcn_mfma_f32_16x16x32_bf16(W1_, a0, acc[0][1], 0, 0, 0); \
    acc[0][2] = __builtin_amdgcn_mfma_f32_16x16x32_bf16(W2_, a0, acc[0][2], 0, 0, 0); \
    acc[0][3] = __builtin_amdgcn_mfma_f32_16x16x32_bf16(W3_, a0, acc[0][3], 0, 0, 0); \
    acc[1][0] = __builtin_amdgcn_mfma_f32_16x16x32_bf16(W0_, a1, acc[1][0], 0, 0, 0); \
    acc[1][1] = __builtin_amdgcn_mfma_f32_16x16x32_bf16(W1_, a1, acc[1][1], 0, 0, 0); \
    acc[1][2] = __builtin_amdgcn_mfma_f32_16x16x32_bf16(W2_, a1, acc[1][2], 0, 0, 0); \
    acc[1][3] = __builtin_amdgcn_mfma_f32_16x16x32_bf16(W3_, a1, acc[1][3], 0, 0, 0); \
    acc[2][0] = __builtin_amdgcn_mfma_f32_16x16x32_bf16(W0_, a2, acc[2][0], 0, 0, 0); \
    acc[2][1] = __builtin_amdgcn_mfma_f32_16x16x32_bf16(W1_, a2, acc[2][1], 0, 0, 0); \
    acc[2][2] = __builtin_amdgcn_mfma_f32_16x16x32_bf16(W2_, a2, acc[2][2], 0, 0, 0); \
    acc[2][3] = __builtin_amdgcn_mfma_f32_16x16x32_bf16(W3_, a2, acc[2][3], 0, 0, 0); \
    acc[3][0] = __builtin_amdgcn_mfma_f32_16x16x32_bf16(W0_, a3, acc[3][0], 0, 0, 0); \
    acc[3][1] = __builtin_amdgcn_mfma_f32_16x16x32_bf16(W1_, a3, acc[3][1], 0, 0, 0); \
    acc[3][2] = __builtin_amdgcn_mfma_f32_16x16x32_bf16(W2_, a3, acc[3][2], 0, 0, 0); \
    acc[3][3] = __builtin_amdgcn_mfma_f32_16x16x32_bf16(W3_, a3, acc[3][3], 0, 0, 0); \
    __builtin_amdgcn_s_setprio(0);                                               \
  }

// K-steps 0..7, consuming alternating slots, prefetching kt+2 (then next layer)
#define DENSE_PIPE(WB, NWB)                                                      \
  KSTEP(wa0,wa1,wa2,wa3, 0) LOADW4(wa0,wa1,wa2,wa3, WB, 2)                       \
  KSTEP(wb0,wb1,wb2,wb3, 1) LOADW4(wb0,wb1,wb2,wb3, WB, 3)                       \
  KSTEP(wa0,wa1,wa2,wa3, 2) LOADW4(wa0,wa1,wa2,wa3, WB, 4)                       \
  KSTEP(wb0,wb1,wb2,wb3, 3) LOADW4(wb0,wb1,wb2,wb3, WB, 5)                       \
  KSTEP(wa0,wa1,wa2,wa3, 4) LOADW4(wa0,wa1,wa2,wa3, WB, 6)                       \
  KSTEP(wb0,wb1,wb2,wb3, 5) LOADW4(wb0,wb1,wb2,wb3, WB, 7)                       \
  KSTEP(wa0,wa1,wa2,wa3, 6) LOADW4(wa0,wa1,wa2,wa3, NWB, 0)                      \
  KSTEP(wb0,wb1,wb2,wb3, 7) LOADW4(wb0,wb1,wb2,wb3, NWB, 1)

#define DENSE_LAST(WB)                                                           \
  KSTEP(wa0,wa1,wa2,wa3, 0) LOADW4(wa0,wa1,wa2,wa3, WB, 2)                       \
  KSTEP(wb0,wb1,wb2,wb3, 1) LOADW4(wb0,wb1,wb2,wb3, WB, 3)                       \
  KSTEP(wa0,wa1,wa2,wa3, 2) LOADW4(wa0,wa1,wa2,wa3, WB, 4)                       \
  KSTEP(wb0,wb1,wb2,wb3, 3) LOADW4(wb0,wb1,wb2,wb3, WB, 5)                       \
  KSTEP(wa0,wa1,wa2,wa3, 4) LOADW4(wa0,wa1,wa2,wa3, WB, 6)                       \
  KSTEP(wb0,wb1,wb2,wb3, 5) LOADW4(wb0,wb1,wb2,wb3, WB, 7)                       \
  KSTEP(wa0,wa1,wa2,wa3, 6)                                                      \
  KSTEP(wb0,wb1,wb2,wb3, 7)

// bias + ReLU + bf16-pack + ds_write_b64 store of acc into ldsAct
#define ACT_STORE(BIAS)                                                          \
  {                                                                              \
    float4 bv0 = *reinterpret_cast<const float4*>((BIAS) + (cgrp * 4 + 0) * 16 + khalf * 4); \
    float4 bv1 = *reinterpret_cast<const float4*>((BIAS) + (cgrp * 4 + 1) * 16 + khalf * 4); \
    float4 bv2 = *reinterpret_cast<const float4*>((BIAS) + (cgrp * 4 + 2) * 16 + khalf * 4); \
    float4 bv3 = *reinterpret_cast<const float4*>((BIAS) + (cgrp * 4 + 3) * 16 + khalf * 4); \
    _Pragma("unroll")                                                            \
    for (int rt = 0; rt < 4; ++rt) {                                             \
      int m = rt * 16 + colb;                                                    \
      unsigned int sbase = (unsigned int)(m * 512);                              \
      unsigned int swz   = (unsigned int)((m & 15) << 4);                        \
      _Pragma("unroll")                                                          \
      for (int ct = 0; ct < 4; ++ct) {                                           \
        float4 bv = (ct == 0) ? bv0 : (ct == 1) ? bv1 : (ct == 2) ? bv2 : bv3;   \
        int n0 = (cgrp * 4 + ct) * 16 + khalf * 4;                               \
        float v0 = fmaxf(acc[rt][ct][0] + bv.x, 0.f);                            \
        float v1 = fmaxf(acc[rt][ct][1] + bv.y, 0.f);                            \
        float v2 = fmaxf(acc[rt][ct][2] + bv.z, 0.f);                            \
        float v3 = fmaxf(acc[rt][ct][3] + bv.w, 0.f);                            \
        unsigned int p0, p1;                                                     \
        asm("v_cvt_pk_bf16_f32 %0, %1, %2" : "=v"(p0) : "v"(v0), "v"(v1));       \
        asm("v_cvt_pk_bf16_f32 %0, %1, %2" : "=v"(p1) : "v"(v2), "v"(v3));       \
        uint2 pk; pk.x = p0; pk.y = p1;                                          \
        *reinterpret_cast<uint2*>(ldsAct + ((sbase + (unsigned int)(n0 * 2)) ^ swz)) = pk; \
      }                                                                          \
    }                                                                            \
  }

__global__ __launch_bounds__(256, 4)
void mlp_kernel(const float* __restrict__ x, const float* __restrict__ h,
                const float* __restrict__ b0, const float* __restrict__ b1,
                const float* __restrict__ b2, const float* __restrict__ b3,
                const unsigned short* __restrict__ wp,
                float* __restrict__ fbuf) {
  __shared__ __align__(16) unsigned char ldsAct[64 * 512];   // 32 KiB TOTAL
  unsigned char* ldsIn = ldsAct;       // layer-0 input overlays first 4 KB

  int tid  = threadIdx.x;
  int wv   = tid >> 6;
  int lane = tid & 63;
  int cgrp = wv;                 // 0..3 : 64-neuron group; wave owns all 64 rows
  int colb  = lane & 15;
  int khalf = lane >> 4;
  int R0 = blockIdx.x * MBLK;

  const unsigned short* wb1p = wp + W0P_ELEMS;
  const unsigned short* wb2p = wp + W0P_ELEMS + W1P_ELEMS;
  const unsigned short* w3p  = wp + W0P_ELEMS + 2 * W1P_ELEMS;

  bf8 wa0, wa1, wa2, wa3, wb0, wb1, wb2, wb3;
  // layer-0 weights (single K-step) into slot A, issued before input staging
  LOADW4(wa0, wa1, wa2, wa3, wp, 0);

  // ---- stage layer-0 input [64 rows][32 bf16] into ldsIn (= ldsAct[0:4K]) ----
  {
    int r = tid >> 2;                   // 0..63
    int q = tid & 3;                    // 8-col chunk
    int gr = R0 + r;
    unsigned int bd = (unsigned int)gr / NS;
    int s = gr - (int)bd * NS;
    float xv = x[bd];
    float node = xv * (cosf((float)s * 0.15707963267948966f) + 1.0f) * 0.5f;
    const float* hrow = h + bd * NCOND;
    us8 au;
#pragma unroll
    for (int i = 0; i < 8; ++i) {
      int c = q * 8 + i;
      float v;
      if (c == 0)       v = node;
      else if (c <= 30) v = hrow[c - 1];
      else              v = 0.0f;
      au[i] = f2bf(v);
    }
    unsigned int off = (unsigned int)(r * 64 + q * 16) ^ (unsigned int)((r & 3) << 4);
    *reinterpret_cast<us8*>(ldsIn + off) = au;
  }
  __syncthreads();

  fx4 acc[4][4];

  // ======== layer 0: K=32 (one K-step), read ldsIn, barrier, store ldsAct ====
  {
    ACC_ZERO;
#pragma unroll
    for (int rt = 0; rt < 4; ++rt) {
      int m = rt * 16 + colb;
      unsigned int off = (unsigned int)(m * 64 + khalf * 16) ^ (unsigned int)((m & 3) << 4);
      bf8 a = *reinterpret_cast<const bf8*>(ldsIn + off);
      acc[rt][0] = __builtin_amdgcn_mfma_f32_16x16x32_bf16(wa0, a, acc[rt][0], 0, 0, 0);
      acc[rt][1] = __builtin_amdgcn_mfma_f32_16x16x32_bf16(wa1, a, acc[rt][1], 0, 0, 0);
      acc[rt][2] = __builtin_amdgcn_mfma_f32_16x16x32_bf16(wa2, a, acc[rt][2], 0, 0, 0);
      acc[rt][3] = __builtin_amdgcn_mfma_f32_16x16x32_bf16(wa3, a, acc[rt][3], 0, 0, 0);
    }
    // prefetch layer-1 kt0/kt1; loads straddle the barrier + store phase
    LOADW4(wa0, wa1, wa2, wa3, wb1p, 0);
    LOADW4(wb0, wb1, wb2, wb3, wb1p, 1);
    __syncthreads();                     // input region fully read by ALL waves
    ACT_STORE(b0);                       // now safe: overwrites overlay region
  }
  __syncthreads();

  // ======== layer 1 (in-place: read, barrier, store, barrier) ========
  ACC_ZERO;
  DENSE_PIPE(wb1p, wb2p);                // tail prefetches layer-2 kt0/kt1
  __syncthreads();
  ACT_STORE(b1);
  __syncthreads();

  // ======== layer 2 ========
  ACC_ZERO;
  DENSE_LAST(wb2p);
  __syncthreads();
  ACT_STORE(b2);
  __syncthreads();

  // ======== layer 3: 256 -> 1 via MFMA, wave wv handles rows wv*16..wv*16+15 ==
  {
    fx4 a3 = fx4{0.f, 0.f, 0.f, 0.f};
    int m = wv * 16 + colb;
    unsigned int abase = (unsigned int)(m * 512 + khalf * 16);
    unsigned int aswz  = (unsigned int)((m & 15) << 4);
#pragma unroll
    for (int kt = 0; kt < 8; ++kt) {
      bf8 w3f = *reinterpret_cast<const bf8*>(w3p + (kt * 64 + lane) * 8);
      bf8 a = *reinterpret_cast<const bf8*>(ldsAct + ((abase + (unsigned)(kt * 64)) ^ aswz));
      a3 = __builtin_amdgcn_mfma_f32_16x16x32_bf16(w3f, a, a3, 0, 0, 0);
    }
    if (lane < 16) {
      float y = a3[0] + b3[0];
      float f = (y > 0.f) ? (y + 1.f) : expf(y);   // elu(y)+1
      fbuf[R0 + wv * 16 + lane] = f;
    }
  }
}

// ---------------- kernel 3: Clenshaw-Curtis reduction -> z, jac ----------------
__global__ void reduce_kernel(const float* __restrict__ x, const float* __restrict__ h,
                              const float* __restrict__ fbuf, float* __restrict__ out) {
  __shared__ float ccw[NS];
  int tid = threadIdx.x;
  if (tid < NS) {
    double acc = 0.0;
#pragma unroll
    for (int i = 0; i <= 20; i += 2) {
      double wi = (i == 0) ? 1.0 : 2.0 / (1.0 - (double)(i * i));
      acc += cos((double)(i * tid) * 3.141592653589793 / 20.0) * wi;
    }
    double edge = (tid == 0 || tid == 20) ? 0.5 : 1.0;
    ccw[tid] = (float)(acc * 0.1 * edge);          // * 2/nb_steps * edge
  }
  __syncthreads();
  int t = blockIdx.x * blockDim.x + tid;
  if (t >= NBD) return;
  const float* fb = fbuf + t * NS;
  float acc = 0.f;
#pragma unroll
  for (int i = 0; i < NS; ++i) acc += fb[i] * ccw[i];
  float z = acc * x[t] * 0.5f + h[t * NCOND];
  out[t] = z;                     // z_est + h[:,:,0]
  out[NBD + t] = fb[0];           // jac = f at node s=0 (steps[0]==1 -> input == [x,h])
}

// ---------------- launcher ----------------
extern "C" void kernel_launch(void* const* d_in, const int* in_sizes, int n_in,
                              void* d_out, int out_size, void* d_ws, size_t ws_size,
                              hipStream_t stream) {
  (void)in_sizes; (void)n_in; (void)out_size; (void)ws_size;
  const float* x  = (const float*)d_in[0];
  const float* h  = (const float*)d_in[1];
  const float* W0 = (const float*)d_in[2];
  const float* b0 = (const float*)d_in[3];
  const float* W1 = (const float*)d_in[4];
  const float* b1 = (const float*)d_in[5];
  const float* W2 = (const float*)d_in[6];
  const float* b2 = (const float*)d_in[7];
  const float* W3 = (const float*)d_in[8];
  const float* b3 = (const float*)d_in[9];

  unsigned short* wp = (unsigned short*)d_ws;
  float* fbuf = (float*)((char*)d_ws + WP_TOTAL * sizeof(unsigned short));
  float* out  = (float*)d_out;

  prep_pack<<<(WP_TOTAL / 8 + 255) / 256, 256, 0, stream>>>(W0, W1, W2, W3, wp);
  mlp_kernel<<<NBLOCKS, 256, 0, stream>>>(x, h, b0, b1, b2, b3, wp, fbuf);
  reduce_kernel<<<(NBD + 255) / 256, 256, 0, stream>>>(x, h, fbuf, out);
}

// Round 10
// 104.083 us; speedup vs baseline: 2.3148x; 2.3148x over previous
//
#include <hip/hip_runtime.h>
#include <math.h>

// ---------------- problem constants ----------------
#define NB        512
#define ND        32
#define NCOND     30
#define NS        21                  // NB_STEPS+1 quadrature nodes
#define NBD       (NB*ND)             // 16384
#define NROWS     (NBD*NS)            // 344064 MLP evaluations
#define MBLK      64                  // rows per block
#define NBLOCKS   (NROWS/MBLK)        // 5376

// packed-weight element counts (ushort)
#define W0P_ELEMS (1*16*64*8)         // 8192
#define W1P_ELEMS (8*16*64*8)         // 65536
#define W3P_ELEMS (8*64*8)            // 4096  (zero-padded W3 as A-fragments)
#define WP_TOTAL  (W0P_ELEMS + 2*W1P_ELEMS + W3P_ELEMS)  // 143360

typedef __bf16 bf8 __attribute__((ext_vector_type(8)));
typedef float  fx4 __attribute__((ext_vector_type(4)));
typedef unsigned short us8 __attribute__((ext_vector_type(8)));

__device__ __forceinline__ unsigned short f2bf(float f) {
  unsigned int u = __float_as_uint(f);
  u += 0x7FFFu + ((u >> 16) & 1u);        // round-to-nearest-even
  return (unsigned short)(u >> 16);
}

// ---------------- kernel 1: pack weights to bf16 MFMA fragment order ----------
__global__ void prep_pack(const float* __restrict__ W0,
                          const float* __restrict__ W1,
                          const float* __restrict__ W2,
                          const float* __restrict__ W3,
                          unsigned short* __restrict__ wp) {
  int t = blockIdx.x * blockDim.x + threadIdx.x;   // one thread = one 8-elem frag
  if (t >= WP_TOTAL / 8) return;
  int base = t * 8;
  us8 out;
  if (base >= W0P_ELEMS + 2 * W1P_ELEMS) {         // W3 region
    int rem  = base - (W0P_ELEMS + 2 * W1P_ELEMS);
    int lane = (rem >> 3) & 63;
    int ktl  = rem >> 9;
    int k0   = ktl * 32 + (lane >> 4) * 8;
#pragma unroll
    for (int i = 0; i < 8; ++i)
      out[i] = ((lane & 15) == 0) ? f2bf(W3[k0 + i]) : (unsigned short)0;
  } else {
    const float* W; int rem, K;
    if (base < W0P_ELEMS)                  { W = W0; rem = base;                 K = 31;  }
    else if (base < W0P_ELEMS + W1P_ELEMS) { W = W1; rem = base - W0P_ELEMS;     K = 256; }
    else                                   { W = W2; rem = base - W0P_ELEMS - W1P_ELEMS; K = 256; }
    int lane = (rem >> 3) & 63;
    int ct   = (rem >> 9) & 15;
    int ktl  =  rem >> 13;
    int j  = ct * 16 + (lane & 15);
    int k0 = ktl * 32 + (lane >> 4) * 8;
#pragma unroll
    for (int i = 0; i < 8; ++i) {
      int k = k0 + i;
      out[i] = (k < K) ? f2bf(W[k * 256 + j]) : (unsigned short)0;
    }
  }
  *reinterpret_cast<us8*>(wp + base) = out;
}

// ---------------- fused MLP kernel ----------------
// 4 waves/block (256 thr), block = 64 rows. Wave wv owns ALL 64 rows
// (4 row-tiles) x 64 neurons (cgrp = wv). 4 independent 4-wave barrier groups
// per CU. LAUNCH BOUNDS: empirical rule on this toolchain (R4-R9 regression):
// VGPR cap = 256/arg2 regardless of block size ((512,4)->64, (512,2)->128,
// (256,4)->64 spilled!). (256,2) -> cap 128 >= ~108 needed, spill-free;
// HW occupancy self-limits at 4 waves/SIMD = 4 blocks/CU (LDS 128KB/CU OK).
// In-place 32KB act buffer + depth-2 weight pipeline + setprio unchanged.

#define ACC_ZERO                                                                 \
  _Pragma("unroll")                                                              \
  for (int rt = 0; rt < 4; ++rt)                                                 \
    _Pragma("unroll")                                                            \
    for (int ct = 0; ct < 4; ++ct) acc[rt][ct] = fx4{0.f, 0.f, 0.f, 0.f};

#define LOADW4(S0,S1,S2,S3, WB, KT)                                              \
  S0 = *reinterpret_cast<const bf8*>((WB) + (((KT) * 16 + cgrp * 4 + 0) * 64 + lane) * 8); \
  S1 = *reinterpret_cast<const bf8*>((WB) + (((KT) * 16 + cgrp * 4 + 1) * 64 + lane) * 8); \
  S2 = *reinterpret_cast<const bf8*>((WB) + (((KT) * 16 + cgrp * 4 + 2) * 64 + lane) * 8); \
  S3 = *reinterpret_cast<const bf8*>((WB) + (((KT) * 16 + cgrp * 4 + 3) * 64 + lane) * 8);

#define KSTEP(W0_,W1_,W2_,W3_, KT)                                               \
  {                                                                              \
    int m0 =  0 + colb;                                                          \
    int m1 = 16 + colb;                                                          \
    int m2 = 32 + colb;                                                          \
    int m3 = 48 + colb;                                                          \
    bf8 a0 = *reinterpret_cast<const bf8*>(ldsAct + (((unsigned)(m0 * 512 + (KT) * 64 + khalf * 16)) ^ ((unsigned)((m0 & 15) << 4)))); \
    bf8 a1 = *reinterpret_cast<const bf8*>(ldsAct + (((unsigned)(m1 * 512 + (KT) * 64 + khalf * 16)) ^ ((unsigned)((m1 & 15) << 4)))); \
    bf8 a2 = *reinterpret_cast<const bf8*>(ldsAct + (((unsigned)(m2 * 512 + (KT) * 64 + khalf * 16)) ^ ((unsigned)((m2 & 15) << 4)))); \
    bf8 a3 = *reinterpret_cast<const bf8*>(ldsAct + (((unsigned)(m3 * 512 + (KT) * 64 + khalf * 16)) ^ ((unsigned)((m3 & 15) << 4)))); \
    __builtin_amdgcn_s_setprio(1);                                               \
    acc[0][0] = __builtin_amdgcn_mfma_f32_16x16x32_bf16(W0_, a0, acc[0][0], 0, 0, 0); \
    acc[0][1] = __builtin_amdgcn_mfma_f32_16x16x32_bf16(W1_, a0, acc[0][1], 0, 0, 0); \
    acc[0][2] = __builtin_amdgcn_mfma_f32_16x16x32_bf16(W2_, a0, acc[0][2], 0, 0, 0); \
    acc[0][3] = __builtin_amdgcn_mfma_f32_16x16x32_bf16(W3_, a0, acc[0][3], 0, 0, 0); \
    acc[1][0] = __builtin_amdgcn_mfma_f32_16x16x32_bf16(W0_, a1, acc[1][0], 0, 0, 0); \
    acc[1][1] = __builtin_amdgcn_mfma_f32_16x16x32_bf16(W1_, a1, acc[1][1], 0, 0, 0); \
    acc[1][2] = __builtin_amdgcn_mfma_f32_16x16x32_bf16(W2_, a1, acc[1][2], 0, 0, 0); \
    acc[1][3] = __builtin_amdgcn_mfma_f32_16x16x32_bf16(W3_, a1, acc[1][3], 0, 0, 0); \
    acc[2][0] = __builtin_amdgcn_mfma_f32_16x16x32_bf16(W0_, a2, acc[2][0], 0, 0, 0); \
    acc[2][1] = __builtin_amdgcn_mfma_f32_16x16x32_bf16(W1_, a2, acc[2][1], 0, 0, 0); \
    acc[2][2] = __builtin_amdgcn_mfma_f32_16x16x32_bf16(W2_, a2, acc[2][2], 0, 0, 0); \
    acc[2][3] = __builtin_amdgcn_mfma_f32_16x16x32_bf16(W3_, a2, acc[2][3], 0, 0, 0); \
    acc[3][0] = __builtin_amdgcn_mfma_f32_16x16x32_bf16(W0_, a3, acc[3][0], 0, 0, 0); \
    acc[3][1] = __builtin_amdgcn_mfma_f32_16x16x32_bf16(W1_, a3, acc[3][1], 0, 0, 0); \
    acc[3][2] = __builtin_amdgcn_mfma_f32_16x16x32_bf16(W2_, a3, acc[3][2], 0, 0, 0); \
    acc[3][3] = __builtin_amdgcn_mfma_f32_16x16x32_bf16(W3_, a3, acc[3][3], 0, 0, 0); \
    __builtin_amdgcn_s_setprio(0);                                               \
  }

// K-steps 0..7, consuming alternating slots, prefetching kt+2 (then next layer)
#define DENSE_PIPE(WB, NWB)                                                      \
  KSTEP(wa0,wa1,wa2,wa3, 0) LOADW4(wa0,wa1,wa2,wa3, WB, 2)                       \
  KSTEP(wb0,wb1,wb2,wb3, 1) LOADW4(wb0,wb1,wb2,wb3, WB, 3)                       \
  KSTEP(wa0,wa1,wa2,wa3, 2) LOADW4(wa0,wa1,wa2,wa3, WB, 4)                       \
  KSTEP(wb0,wb1,wb2,wb3, 3) LOADW4(wb0,wb1,wb2,wb3, WB, 5)                       \
  KSTEP(wa0,wa1,wa2,wa3, 4) LOADW4(wa0,wa1,wa2,wa3, WB, 6)                       \
  KSTEP(wb0,wb1,wb2,wb3, 5) LOADW4(wb0,wb1,wb2,wb3, WB, 7)                       \
  KSTEP(wa0,wa1,wa2,wa3, 6) LOADW4(wa0,wa1,wa2,wa3, NWB, 0)                      \
  KSTEP(wb0,wb1,wb2,wb3, 7) LOADW4(wb0,wb1,wb2,wb3, NWB, 1)

#define DENSE_LAST(WB)                                                           \
  KSTEP(wa0,wa1,wa2,wa3, 0) LOADW4(wa0,wa1,wa2,wa3, WB, 2)                       \
  KSTEP(wb0,wb1,wb2,wb3, 1) LOADW4(wb0,wb1,wb2,wb3, WB, 3)                       \
  KSTEP(wa0,wa1,wa2,wa3, 2) LOADW4(wa0,wa1,wa2,wa3, WB, 4)                       \
  KSTEP(wb0,wb1,wb2,wb3, 3) LOADW4(wb0,wb1,wb2,wb3, WB, 5)                       \
  KSTEP(wa0,wa1,wa2,wa3, 4) LOADW4(wa0,wa1,wa2,wa3, WB, 6)                       \
  KSTEP(wb0,wb1,wb2,wb3, 5) LOADW4(wb0,wb1,wb2,wb3, WB, 7)                       \
  KSTEP(wa0,wa1,wa2,wa3, 6)                                                      \
  KSTEP(wb0,wb1,wb2,wb3, 7)

// bias + ReLU + bf16-pack + ds_write_b64 store of acc into ldsAct
#define ACT_STORE(BIAS)                                                          \
  {                                                                              \
    float4 bv0 = *reinterpret_cast<const float4*>((BIAS) + (cgrp * 4 + 0) * 16 + khalf * 4); \
    float4 bv1 = *reinterpret_cast<const float4*>((BIAS) + (cgrp * 4 + 1) * 16 + khalf * 4); \
    float4 bv2 = *reinterpret_cast<const float4*>((BIAS) + (cgrp * 4 + 2) * 16 + khalf * 4); \
    float4 bv3 = *reinterpret_cast<const float4*>((BIAS) + (cgrp * 4 + 3) * 16 + khalf * 4); \
    _Pragma("unroll")                                                            \
    for (int rt = 0; rt < 4; ++rt) {                                             \
      int m = rt * 16 + colb;                                                    \
      unsigned int sbase = (unsigned int)(m * 512);                              \
      unsigned int swz   = (unsigned int)((m & 15) << 4);                        \
      _Pragma("unroll")                                                          \
      for (int ct = 0; ct < 4; ++ct) {                                           \
        float4 bv = (ct == 0) ? bv0 : (ct == 1) ? bv1 : (ct == 2) ? bv2 : bv3;   \
        int n0 = (cgrp * 4 + ct) * 16 + khalf * 4;                               \
        float v0 = fmaxf(acc[rt][ct][0] + bv.x, 0.f);                            \
        float v1 = fmaxf(acc[rt][ct][1] + bv.y, 0.f);                            \
        float v2 = fmaxf(acc[rt][ct][2] + bv.z, 0.f);                            \
        float v3 = fmaxf(acc[rt][ct][3] + bv.w, 0.f);                            \
        unsigned int p0, p1;                                                     \
        asm("v_cvt_pk_bf16_f32 %0, %1, %2" : "=v"(p0) : "v"(v0), "v"(v1));       \
        asm("v_cvt_pk_bf16_f32 %0, %1, %2" : "=v"(p1) : "v"(v2), "v"(v3));       \
        uint2 pk; pk.x = p0; pk.y = p1;                                          \
        *reinterpret_cast<uint2*>(ldsAct + ((sbase + (unsigned int)(n0 * 2)) ^ swz)) = pk; \
      }                                                                          \
    }                                                                            \
  }

__global__ __launch_bounds__(256, 2)
void mlp_kernel(const float* __restrict__ x, const float* __restrict__ h,
                const float* __restrict__ b0, const float* __restrict__ b1,
                const float* __restrict__ b2, const float* __restrict__ b3,
                const unsigned short* __restrict__ wp,
                float* __restrict__ fbuf) {
  __shared__ __align__(16) unsigned char ldsAct[64 * 512];   // 32 KiB TOTAL
  unsigned char* ldsIn = ldsAct;       // layer-0 input overlays first 4 KB

  int tid  = threadIdx.x;
  int wv   = tid >> 6;
  int lane = tid & 63;
  int cgrp = wv;                 // 0..3 : 64-neuron group; wave owns all 64 rows
  int colb  = lane & 15;
  int khalf = lane >> 4;
  int R0 = blockIdx.x * MBLK;

  const unsigned short* wb1p = wp + W0P_ELEMS;
  const unsigned short* wb2p = wp + W0P_ELEMS + W1P_ELEMS;
  const unsigned short* w3p  = wp + W0P_ELEMS + 2 * W1P_ELEMS;

  bf8 wa0, wa1, wa2, wa3, wb0, wb1, wb2, wb3;
  // layer-0 weights (single K-step) into slot A, issued before input staging
  LOADW4(wa0, wa1, wa2, wa3, wp, 0);

  // ---- stage layer-0 input [64 rows][32 bf16] into ldsIn (= ldsAct[0:4K]) ----
  {
    int r = tid >> 2;                   // 0..63
    int q = tid & 3;                    // 8-col chunk
    int gr = R0 + r;
    unsigned int bd = (unsigned int)gr / NS;
    int s = gr - (int)bd * NS;
    float xv = x[bd];
    float node = xv * (cosf((float)s * 0.15707963267948966f) + 1.0f) * 0.5f;
    const float* hrow = h + bd * NCOND;
    us8 au;
#pragma unroll
    for (int i = 0; i < 8; ++i) {
      int c = q * 8 + i;
      float v;
      if (c == 0)       v = node;
      else if (c <= 30) v = hrow[c - 1];
      else              v = 0.0f;
      au[i] = f2bf(v);
    }
    unsigned int off = (unsigned int)(r * 64 + q * 16) ^ (unsigned int)((r & 3) << 4);
    *reinterpret_cast<us8*>(ldsIn + off) = au;
  }
  __syncthreads();

  fx4 acc[4][4];

  // ======== layer 0: K=32 (one K-step), read ldsIn, barrier, store ldsAct ====
  {
    ACC_ZERO;
#pragma unroll
    for (int rt = 0; rt < 4; ++rt) {
      int m = rt * 16 + colb;
      unsigned int off = (unsigned int)(m * 64 + khalf * 16) ^ (unsigned int)((m & 3) << 4);
      bf8 a = *reinterpret_cast<const bf8*>(ldsIn + off);
      acc[rt][0] = __builtin_amdgcn_mfma_f32_16x16x32_bf16(wa0, a, acc[rt][0], 0, 0, 0);
      acc[rt][1] = __builtin_amdgcn_mfma_f32_16x16x32_bf16(wa1, a, acc[rt][1], 0, 0, 0);
      acc[rt][2] = __builtin_amdgcn_mfma_f32_16x16x32_bf16(wa2, a, acc[rt][2], 0, 0, 0);
      acc[rt][3] = __builtin_amdgcn_mfma_f32_16x16x32_bf16(wa3, a, acc[rt][3], 0, 0, 0);
    }
    // prefetch layer-1 kt0/kt1; loads straddle the barrier + store phase
    LOADW4(wa0, wa1, wa2, wa3, wb1p, 0);
    LOADW4(wb0, wb1, wb2, wb3, wb1p, 1);
    __syncthreads();                     // input region fully read by ALL waves
    ACT_STORE(b0);                       // now safe: overwrites overlay region
  }
  __syncthreads();

  // ======== layer 1 (in-place: read, barrier, store, barrier) ========
  ACC_ZERO;
  DENSE_PIPE(wb1p, wb2p);                // tail prefetches layer-2 kt0/kt1
  __syncthreads();
  ACT_STORE(b1);
  __syncthreads();

  // ======== layer 2 ========
  ACC_ZERO;
  DENSE_LAST(wb2p);
  __syncthreads();
  ACT_STORE(b2);
  __syncthreads();

  // ======== layer 3: 256 -> 1 via MFMA, wave wv handles rows wv*16..wv*16+15 ==
  {
    fx4 a3 = fx4{0.f, 0.f, 0.f, 0.f};
    int m = wv * 16 + colb;
    unsigned int abase = (unsigned int)(m * 512 + khalf * 16);
    unsigned int aswz  = (unsigned int)((m & 15) << 4);
#pragma unroll
    for (int kt = 0; kt < 8; ++kt) {
      bf8 w3f = *reinterpret_cast<const bf8*>(w3p + (kt * 64 + lane) * 8);
      bf8 a = *reinterpret_cast<const bf8*>(ldsAct + ((abase + (unsigned)(kt * 64)) ^ aswz));
      a3 = __builtin_amdgcn_mfma_f32_16x16x32_bf16(w3f, a, a3, 0, 0, 0);
    }
    if (lane < 16) {
      float y = a3[0] + b3[0];
      float f = (y > 0.f) ? (y + 1.f) : expf(y);   // elu(y)+1
      fbuf[R0 + wv * 16 + lane] = f;
    }
  }
}

// ---------------- kernel 3: Clenshaw-Curtis reduction -> z, jac ----------------
__global__ void reduce_kernel(const float* __restrict__ x, const float* __restrict__ h,
                              const float* __restrict__ fbuf, float* __restrict__ out) {
  __shared__ float ccw[NS];
  int tid = threadIdx.x;
  if (tid < NS) {
    double acc = 0.0;
#pragma unroll
    for (int i = 0; i <= 20; i += 2) {
      double wi = (i == 0) ? 1.0 : 2.0 / (1.0 - (double)(i * i));
      acc += cos((double)(i * tid) * 3.141592653589793 / 20.0) * wi;
    }
    double edge = (tid == 0 || tid == 20) ? 0.5 : 1.0;
    ccw[tid] = (float)(acc * 0.1 * edge);          // * 2/nb_steps * edge
  }
  __syncthreads();
  int t = blockIdx.x * blockDim.x + tid;
  if (t >= NBD) return;
  const float* fb = fbuf + t * NS;
  float acc = 0.f;
#pragma unroll
  for (int i = 0; i < NS; ++i) acc += fb[i] * ccw[i];
  float z = acc * x[t] * 0.5f + h[t * NCOND];
  out[t] = z;                     // z_est + h[:,:,0]
  out[NBD + t] = fb[0];           // jac = f at node s=0 (steps[0]==1 -> input == [x,h])
}

// ---------------- launcher ----------------
extern "C" void kernel_launch(void* const* d_in, const int* in_sizes, int n_in,
                              void* d_out, int out_size, void* d_ws, size_t ws_size,
                              hipStream_t stream) {
  (void)in_sizes; (void)n_in; (void)out_size; (void)ws_size;
  const float* x  = (const float*)d_in[0];
  const float* h  = (const float*)d_in[1];
  const float* W0 = (const float*)d_in[2];
  const float* b0 = (const float*)d_in[3];
  const float* W1 = (const float*)d_in[4];
  const float* b1 = (const float*)d_in[5];
  const float* W2 = (const float*)d_in[6];
  const float* b2 = (const float*)d_in[7];
  const float* W3 = (const float*)d_in[8];
  const float* b3 = (const float*)d_in[9];

  unsigned short* wp = (unsigned short*)d_ws;
  float* fbuf = (float*)((char*)d_ws + WP_TOTAL * sizeof(unsigned short));
  float* out  = (float*)d_out;

  prep_pack<<<(WP_TOTAL / 8 + 255) / 256, 256, 0, stream>>>(W0, W1, W2, W3, wp);
  mlp_kernel<<<NBLOCKS, 256, 0, stream>>>(x, h, b0, b1, b2, b3, wp, fbuf);
  reduce_kernel<<<(NBD + 255) / 256, 256, 0, stream>>>(x, h, fbuf, out);
}